// Round 1
// baseline (226.089 us; speedup 1.0000x reference)
//
#include <hip/hip_runtime.h>
#include <stdint.h>

// RandomForest "mean of E linear heads" == single linear head with averaged
// weights:  out[i] = x[i,:] . mean_e(W[e,0,:]) + mean_e(b[e]).   fp32 in/out.
//
// R3 analysis: timed graph = 2x 640MB harness fills (~94us each, 6.8 TB/s)
// + this kernel (~37us incl. graph gaps). Kernel HBM floor: 160MB read +
// 16MB write = 28us @ 6.3 TB/s. This version removes the VGPR round-trip
// in staging (global_load_lds dwordx4, async until the one barrier) and
// uses nontemporal output stores (streaming, zero reuse -> skip L2
// allocate). LDS layout was already linear lane-contiguous (slot=k*BLOCK+t),
// i.e. exactly the wave-uniform-base + lane*16 pattern global_load_lds
// requires -- no layout change.
//
// Block = 320 thr (5 waves), 640 rows/block, 6250 blocks -> no tail
// (6250 * 640 == 4,000,000). LDS = 25.6 KB -> 6 blocks/CU, 30 waves/CU.

#define BLOCK 320
#define ROWS_PER_BLOCK 640           // 2 rows per thread
#define F4_PER_BLOCK (ROWS_PER_BLOCK * 10 / 4)   // 1600
#define F4_PER_THREAD (F4_PER_BLOCK / BLOCK)     // 5

typedef float f32x2 __attribute__((ext_vector_type(2)));

__global__ __launch_bounds__(BLOCK) void rf_mean_linear(
    const float* __restrict__ x,     // [batch, 10]
    const float* __restrict__ W,     // [10, 1, 10]
    const float* __restrict__ bias,  // [10, 1]
    float* __restrict__ out,         // [batch, 1]
    int batch)
{
    __shared__ float4 s_x[F4_PER_BLOCK];   // 25600 B, block's 640 rows row-major
    __shared__ float s_w[10];
    __shared__ float s_b;

    const int t = threadIdx.x;

    if (t < 10) {
        float acc = 0.f;
        #pragma unroll
        for (int e = 0; e < 10; ++e) acc += W[e * 10 + t];
        s_w[t] = acc * 0.1f;
    }
    if (t == 0) {
        float acc = 0.f;
        #pragma unroll
        for (int e = 0; e < 10; ++e) acc += bias[e];
        s_b = acc * 0.1f;
    }

    // Stage: 5 async direct-to-LDS 16B loads per thread. Global src addr is
    // per-lane; LDS dest is the wave-uniform base (slot k*BLOCK + wave*64),
    // HW adds lane*16. Loads sit in the vmcnt queue until the barrier.
    const float4* xf4 = (const float4*)x;
    const long long blk_f4 = (long long)blockIdx.x * F4_PER_BLOCK;
    const int wave_base = t & ~63;          // uniform within each wave
    #pragma unroll
    for (int k = 0; k < F4_PER_THREAD; ++k) {
        const int slot = k * BLOCK + t;     // per-lane global slot
        __builtin_amdgcn_global_load_lds(
            (const __attribute__((address_space(1))) void*)(xf4 + blk_f4 + slot),
            (__attribute__((address_space(3))) void*)(&s_x[k * BLOCK + wave_base]),
            16, 0, 0);
    }
    __syncthreads();   // compiler emits vmcnt(0)+lgkmcnt(0) drain here

    const float bavg = s_b;
    float w[10];
    #pragma unroll
    for (int j = 0; j < 10; ++j) w[j] = s_w[j];

    // Each thread: 2 rows = 80 B contiguous LDS = 5 x ds_read_b128.
    // Bank start (20t + 4q) % 32 -> all 8 four-bank groups hit evenly
    // (8 accesses/bank = inherent b128 minimum, no excess conflict).
    float4 d[5];
    #pragma unroll
    for (int q = 0; q < 5; ++q) d[q] = s_x[t * 5 + q];
    const float* f = (const float*)d;

    float r0 = bavg, r1 = bavg;
    #pragma unroll
    for (int j = 0; j < 10; ++j) r0 = fmaf(f[j],      w[j], r0);
    #pragma unroll
    for (int j = 0; j < 10; ++j) r1 = fmaf(f[10 + j], w[j], r1);

    // Coalesced 8 B nontemporal store: rows (block*640 + 2t, +1).
    // Pure streaming output -> no reuse, skip L2 allocate (nt flag).
    const long long row = (long long)blockIdx.x * ROWS_PER_BLOCK + 2 * t;
    f32x2 res; res.x = r0; res.y = r1;
    __builtin_nontemporal_store(res, (f32x2*)(out + row));
}

extern "C" void kernel_launch(void* const* d_in, const int* in_sizes, int n_in,
                              void* d_out, int out_size, void* d_ws, size_t ws_size,
                              hipStream_t stream) {
    const float* x   = (const float*)d_in[0];
    const float* W   = (const float*)d_in[1];
    const float* b   = (const float*)d_in[2];
    float* out = (float*)d_out;

    const int batch = in_sizes[0] / 10;               // 4,000,000
    const int blocks = batch / ROWS_PER_BLOCK;        // 6250, exact
    rf_mean_linear<<<blocks, BLOCK, 0, stream>>>(x, W, b, out, batch);
}